// Round 7
// baseline (604.161 us; speedup 1.0000x reference)
//
#include <hip/hip_runtime.h>
#include <stdint.h>

#define B_    2
#define CIN   128
#define HIMG  32
#define WIMG  32
#define COUT_ 128
#define PP    1024
#define FTOT  1152
#define NSUB  9
#define NS    8
#define NT    8
#define NROW  18

typedef int v4i __attribute__((ext_vector_type(4)));

// ws layout (bytes)
#define OFF_NORM   0                      // 128 f32
#define OFF_MAXV   512                    // 18 u32
#define OFF_MB     640                    // 18 uint2 (m, b)
#define OFF_PMODE  800                    // 18 i32
#define OFF_LUT    1024                   // 18*132 u8 (fallback gather table)
#define OFF_WQP    4096                   // 128*1152 u8 (packed magnitudes)
#define OFF_WQN    (4096 + 147456)
#define OFF_XQ     (4096 + 2*147456)      // 2*1024*1152 u8  -> ends 2658304
#define OFF_WBY    2658304                // 144 planes * 16384 = 2359296
#define WS_NEED_WBY (OFF_WBY + 2359296)   // 5017600

// Extract bit `sh` of each packed byte -> 0/1 bytes.
__device__ __forceinline__ v4i bitsel(uint4 d, int sh) {
    v4i r;
    r[0] = (int)((d.x >> sh) & 0x01010101u);
    r[1] = (int)((d.y >> sh) & 0x01010101u);
    r[2] = (int)((d.z >> sh) & 0x01010101u);
    r[3] = (int)((d.w >> sh) & 0x01010101u);
    return r;
}

// ---------------------------------------------------------------------------
// Weight prep: per-o norm, f64 quantization (matches np-f64 golden), packed
// magnitudes wqp/wqn; fused phase 2 expands bit-planes to 0/1 bytes (wby).
// ---------------------------------------------------------------------------
__global__ __launch_bounds__(256) void k_prep_w(const float* __restrict__ w,
                                                float* __restrict__ norm_out,
                                                uint8_t* __restrict__ wqp,
                                                uint8_t* __restrict__ wqn,
                                                uint8_t* __restrict__ wby,
                                                int do_expand) {
    int o = blockIdx.x, tid = threadIdx.x;
    __shared__ float red[256];
    __shared__ alignas(16) uint8_t sip[FTOT];
    __shared__ alignas(16) uint8_t sin_[FTOT];
    const float* wo = w + (size_t)o * FTOT;
    float m = 0.f;
    for (int f = tid; f < FTOT; f += 256) m = fmaxf(m, fabsf(wo[f]));
    red[tid] = m;
    __syncthreads();
    for (int s2 = 128; s2 > 0; s2 >>= 1) {
        if (tid < s2) red[tid] = fmaxf(red[tid], red[tid + s2]);
        __syncthreads();
    }
    float norm = red[0];
    if (tid == 0) norm_out[o] = norm;
    for (int f = tid; f < FTOT; f += 256) {
        double wi = rint(((double)wo[f] / (double)norm) * 255.0);
        uint8_t ip = (uint8_t)(int)fmax(wi, 0.0);
        uint8_t in_ = (uint8_t)(int)fmax(-wi, 0.0);
        wqp[(size_t)o * FTOT + f] = ip;
        wqn[(size_t)o * FTOT + f] = in_;
        sip[f] = ip;
        sin_[f] = in_;
    }
    __syncthreads();
    if (do_expand) {
        // e -> (sub, t, sign, q4): one uint4 of plane bytes per iteration
        for (int e = tid; e < 1152; e += 256) {
            int q4 = e & 7, ts = (e >> 3) & 15, sub = e >> 7;
            int sign = ts & 1, t = ts >> 1;
            const uint8_t* src = (sign ? sin_ : sip) + sub * 128 + q4 * 16;
            uint4 d = *(const uint4*)src;
            v4i bits = bitsel(d, t);
            *(v4i*)(wby + (size_t)(((sub * 8 + t) * 2 + sign) * 16384)
                        + o * 128 + q4 * 16) = bits;
        }
    }
}

// ---------------------------------------------------------------------------
// Input prep (proven): im2col + quantize to u8 xq[b][p][f]; zero maxv.
// ---------------------------------------------------------------------------
__global__ __launch_bounds__(256) void k_prep_x(const float* __restrict__ x,
                                                uint8_t* __restrict__ xq,
                                                uint32_t* __restrict__ maxv) {
    if (blockIdx.x == 0 && threadIdx.x < NROW) maxv[threadIdx.x] = 0u;
    int gid = blockIdx.x * 256 + threadIdx.x;    // 2*1024*72 = 147456 exact
    int fg = gid % 72;
    int rest = gid / 72;
    int p = rest & 1023;
    int b = rest >> 10;
    int py = p >> 5, px = p & 31;
    uint32_t dw[4] = {0, 0, 0, 0};
    #pragma unroll
    for (int j = 0; j < 16; ++j) {
        int f = fg * 16 + j;
        int c = f / 9, u = f % 9;
        int kh = u / 3, kw = u % 3;
        int y = py + kh - 1, xx = px + kw - 1;
        uint32_t xi = 0;
        if (y >= 0 && y < HIMG && xx >= 0 && xx < WIMG) {
            float v = x[(((size_t)b * CIN + c) * HIMG + y) * WIMG + xx];
            float q = rintf(v * 256.0f);              // exact: power-of-2 scale
            q = fminf(fmaxf(q, 0.f), 255.f);
            xi = (uint32_t)q;
        }
        dw[j >> 2] |= xi << ((j & 3) * 8);
    }
    *reinterpret_cast<uint4*>(xq + (size_t)((b << 10) + p) * FTOT + fg * 16) =
        make_uint4(dw[0], dw[1], dw[2], dw[3]);
}

// ---------------------------------------------------------------------------
// Pass 1: max pr per (sub, sign). Round-4 structure: block(512)=(b,ot,pt),
// wave = s. WBY: load pre-expanded A-frags; else bitsel packed wq.
// ---------------------------------------------------------------------------
template <bool WBY>
__global__ __launch_bounds__(512) void k_max_t(const uint8_t* __restrict__ xq,
                                               const uint8_t* __restrict__ wqp,
                                               const uint8_t* __restrict__ wqn,
                                               const uint8_t* __restrict__ wby,
                                               uint32_t* __restrict__ maxv) {
    int tid = threadIdx.x, lane = tid & 63, wid = tid >> 6;
    int blk = blockIdx.x;
    int b = blk >> 9, r = blk & 511, ot = r >> 6, pt = r & 63;
    int s = wid;
    int col = lane & 15, kq = lane >> 4;
    int p = pt * 16 + col, oa = ot * 16 + col;
    __shared__ uint32_t smax[8][NSUB][2];

    const uint8_t* xbase = xq + (size_t)((b << 10) + p) * FTOT + kq * 16;
    const uint8_t* wbl = wby + (size_t)oa * 128 + kq * 16;
    const uint8_t* wpb = wqp + (size_t)oa * FTOT + kq * 16;
    const uint8_t* wnb = wqn + (size_t)oa * FTOT + kq * 16;

    for (int sub = 0; sub < NSUB; ++sub) {
        int fo = sub * 128;
        uint4 xg0 = *(const uint4*)(xbase + fo);
        uint4 xg1 = *(const uint4*)(xbase + fo + 64);
        v4i bf0 = bitsel(xg0, s), bf1 = bitsel(xg1, s);
        uint4 wp0, wp1, wn0, wn1;
        if (!WBY) {
            wp0 = *(const uint4*)(wpb + fo); wp1 = *(const uint4*)(wpb + fo + 64);
            wn0 = *(const uint4*)(wnb + fo); wn1 = *(const uint4*)(wnb + fo + 64);
        }
        int mp = 0, mn = 0;
        #pragma unroll
        for (int t = 0; t < NT; ++t) {
            v4i ap0, ap1, an0, an1;
            if (WBY) {
                const uint8_t* pb = wbl + (size_t)(((sub * 8 + t) * 2) * 16384);
                ap0 = *(const v4i*)pb;
                ap1 = *(const v4i*)(pb + 64);
                an0 = *(const v4i*)(pb + 16384);
                an1 = *(const v4i*)(pb + 16384 + 64);
            } else {
                ap0 = bitsel(wp0, t); ap1 = bitsel(wp1, t);
                an0 = bitsel(wn0, t); an1 = bitsel(wn1, t);
            }
            v4i acc = {0, 0, 0, 0};
            acc = __builtin_amdgcn_mfma_i32_16x16x64_i8(ap0, bf0, acc, 0, 0, 0);
            acc = __builtin_amdgcn_mfma_i32_16x16x64_i8(ap1, bf1, acc, 0, 0, 0);
            mp = max(mp, max(max(acc[0], acc[1]), max(acc[2], acc[3])));
            v4i acn = {0, 0, 0, 0};
            acn = __builtin_amdgcn_mfma_i32_16x16x64_i8(an0, bf0, acn, 0, 0, 0);
            acn = __builtin_amdgcn_mfma_i32_16x16x64_i8(an1, bf1, acn, 0, 0, 0);
            mn = max(mn, max(max(acn[0], acn[1]), max(acn[2], acn[3])));
        }
        #pragma unroll
        for (int off = 32; off > 0; off >>= 1) {
            mp = max(mp, __shfl_xor(mp, off));
            mn = max(mn, __shfl_xor(mn, off));
        }
        if (lane == 0) { smax[wid][sub][0] = (uint32_t)mp; smax[wid][sub][1] = (uint32_t)mn; }
    }
    __syncthreads();
    if (tid < NROW) {
        int sub = tid >> 1, sg = tid & 1;
        uint32_t m = 0;
        #pragma unroll
        for (int w2 = 0; w2 < 8; ++w2) m = max(m, smax[w2][sub][sg]);
        atomicMax(&maxv[tid], m);
    }
}

// ---------------------------------------------------------------------------
// k_lut (proven round 6): exact f64 table; integer (m,b) feasibility search
// with floor((pr*m+b)/2^16) == code(pr) for all pr<=vmax; fallback LUT.
// ---------------------------------------------------------------------------
__global__ __launch_bounds__(256) void k_lut(const uint32_t* __restrict__ maxv,
                                             uint8_t* __restrict__ lut,
                                             uint2* __restrict__ mb,
                                             int* __restrict__ pmode) {
    int row = blockIdx.x, tid = threadIdx.x;
    __shared__ uint8_t codes[132];
    __shared__ int bestm;
    if (tid == 0) bestm = 0x7fffffff;
    int vmax = (int)maxv[row];
    for (int pr = tid; pr < 129; pr += 256) {
        double vmaxd = fmax((double)vmax, 1e-6);
        double step = vmaxd / 15.0;
        double q = rint((double)pr / step);
        q = fmin(fmax(q, 0.0), 15.0);
        codes[pr] = (uint8_t)q;
        lut[row * 132 + pr] = (uint8_t)q;
    }
    __syncthreads();
    int ve = max(vmax, 1);
    int m0 = (983040 + ve / 2) / ve;           // ~2^16*15/vmax
    int m = m0 - 128 + tid;
    if (m >= 1) {
        int L = 0, U = 0x7fffffff;
        for (int pr = 0; pr <= vmax && pr <= 128; ++pr) {
            int c = codes[pr];
            int lo = (c << 16) - pr * m;
            int hi = ((c + 1) << 16) - 1 - pr * m;
            L = max(L, lo);
            U = min(U, hi);
            if (L > U) break;
        }
        if (L <= U) atomicMin(&bestm, m);
    }
    __syncthreads();
    if (tid == 0) {
        if (bestm == 0x7fffffff) {
            pmode[row] = 1;
            mb[row] = make_uint2(0u, 0u);
        } else {
            int L = 0;
            for (int pr = 0; pr <= vmax && pr <= 128; ++pr)
                L = max(L, ((int)codes[pr] << 16) - pr * bestm);
            pmode[row] = 0;
            mb[row] = make_uint2((uint32_t)bestm, (uint32_t)L);
        }
    }
}

// ---------------------------------------------------------------------------
// Pass 2: round-4 structure, integer-mad ADC, exact integer sums, f64 scale.
// ---------------------------------------------------------------------------
template <bool WBY>
__global__ __launch_bounds__(512) void k_adc_t(const uint8_t* __restrict__ xq,
                                               const uint8_t* __restrict__ wqp,
                                               const uint8_t* __restrict__ wqn,
                                               const uint8_t* __restrict__ wby,
                                               const uint32_t* __restrict__ maxv,
                                               const uint8_t* __restrict__ lut,
                                               const uint2* __restrict__ mb,
                                               const int* __restrict__ pmode,
                                               const float* __restrict__ norm,
                                               float* __restrict__ out) {
    int tid = threadIdx.x, lane = tid & 63, wid = tid >> 6;
    int blk = blockIdx.x;
    int b = blk >> 9, r = blk & 511, ot = r >> 6, pt = r & 63;
    int s = wid;
    int col = lane & 15, kq = lane >> 4;
    int p = pt * 16 + col, oa = ot * 16 + col;

    __shared__ int lred[8][64][4];

    const uint8_t* xbase = xq + (size_t)((b << 10) + p) * FTOT + kq * 16;
    const uint8_t* wbl = wby + (size_t)oa * 128 + kq * 16;
    const uint8_t* wpb = wqp + (size_t)oa * FTOT + kq * 16;
    const uint8_t* wnb = wqn + (size_t)oa * FTOT + kq * 16;

    int run[4] = {0, 0, 0, 0};
    for (int sub = 0; sub < NSUB; ++sub) {
        int fo = sub * 128;
        uint4 xg0 = *(const uint4*)(xbase + fo);
        uint4 xg1 = *(const uint4*)(xbase + fo + 64);
        v4i bf0 = bitsel(xg0, s), bf1 = bitsel(xg1, s);
        uint4 wp0, wp1, wn0, wn1;
        if (!WBY) {
            wp0 = *(const uint4*)(wpb + fo); wp1 = *(const uint4*)(wpb + fo + 64);
            wn0 = *(const uint4*)(wnb + fo); wn1 = *(const uint4*)(wnb + fo + 64);
        }

        int rowp = sub * 2, rown = sub * 2 + 1;
        uint2 mbp = mb[rowp], mbn = mb[rown];
        int fbp = pmode[rowp], fbn = pmode[rown];
        const uint8_t* glp = lut + rowp * 132;
        const uint8_t* gln = lut + rown * 132;
        int vp = (int)maxv[rowp], vn = (int)maxv[rown];

        uint32_t Sp[4] = {0, 0, 0, 0}, Sn[4] = {0, 0, 0, 0};
        #pragma unroll
        for (int t = 0; t < NT; ++t) {
            v4i ap0, ap1, an0, an1;
            if (WBY) {
                const uint8_t* pb = wbl + (size_t)(((sub * 8 + t) * 2) * 16384);
                ap0 = *(const v4i*)pb;
                ap1 = *(const v4i*)(pb + 64);
                an0 = *(const v4i*)(pb + 16384);
                an1 = *(const v4i*)(pb + 16384 + 64);
            } else {
                ap0 = bitsel(wp0, t); ap1 = bitsel(wp1, t);
                an0 = bitsel(wn0, t); an1 = bitsel(wn1, t);
            }
            v4i acc = {0, 0, 0, 0};
            acc = __builtin_amdgcn_mfma_i32_16x16x64_i8(ap0, bf0, acc, 0, 0, 0);
            acc = __builtin_amdgcn_mfma_i32_16x16x64_i8(ap1, bf1, acc, 0, 0, 0);
            if (fbp == 0) {
                #pragma unroll
                for (int i = 0; i < 4; ++i) {
                    uint32_t v = __umul24((uint32_t)acc[i], mbp.x) + mbp.y;
                    Sp[i] += ((v >> 16) & 15u) << t;
                }
            } else {
                #pragma unroll
                for (int i = 0; i < 4; ++i) Sp[i] += (uint32_t)glp[acc[i]] << t;
            }
            v4i acn = {0, 0, 0, 0};
            acn = __builtin_amdgcn_mfma_i32_16x16x64_i8(an0, bf0, acn, 0, 0, 0);
            acn = __builtin_amdgcn_mfma_i32_16x16x64_i8(an1, bf1, acn, 0, 0, 0);
            if (fbn == 0) {
                #pragma unroll
                for (int i = 0; i < 4; ++i) {
                    uint32_t v = __umul24((uint32_t)acn[i], mbn.x) + mbn.y;
                    Sn[i] += ((v >> 16) & 15u) << t;
                }
            } else {
                #pragma unroll
                for (int i = 0; i < 4; ++i) Sn[i] += (uint32_t)gln[acn[i]] << t;
            }
        }
        // exact: (vp*Sp)*2^s - (vn*Sn)*2^s ; Sp,Sn <= 3825, products < 2^20, <<7 < 2^27
        #pragma unroll
        for (int i = 0; i < 4; ++i)
            run[i] += (int)(__umul24((uint32_t)vp, Sp[i]) << s)
                    - (int)(__umul24((uint32_t)vn, Sn[i]) << s);
    }
    #pragma unroll
    for (int i = 0; i < 4; ++i) lred[wid][lane][i] = run[i];
    __syncthreads();
    if (tid < 256) {
        int lane2 = tid >> 2, i = tid & 3;
        long long s64 = 0;
        #pragma unroll
        for (int w2 = 0; w2 < 8; ++w2) s64 += (long long)lred[w2][lane2][i];
        int o = ot * 16 + (lane2 >> 4) * 4 + i;      // C/D: row=(lane>>4)*4+reg [m89]
        int pp2 = pt * 16 + (lane2 & 15);            // C/D: col=lane&15
        double v = (double)s64 * (double)norm[o] / 15.0 / 255.0 / 256.0;
        out[((size_t)(b * COUT_ + o)) * PP + pp2] = (float)v;
    }
    if (blk == 0 && tid == 0) out[(size_t)B_ * COUT_ * PP] = 0.0f;   // adc_loss
}

// ---------------------------------------------------------------------------
extern "C" void kernel_launch(void* const* d_in, const int* in_sizes, int n_in,
                              void* d_out, int out_size, void* d_ws, size_t ws_size,
                              hipStream_t stream) {
    const float* x = (const float*)d_in[0];
    const float* w = (const float*)d_in[1];
    float* out = (float*)d_out;
    char* ws = (char*)d_ws;

    float* norm = (float*)(ws + OFF_NORM);
    uint32_t* maxv = (uint32_t*)(ws + OFF_MAXV);
    uint2* mb = (uint2*)(ws + OFF_MB);
    int* pmode = (int*)(ws + OFF_PMODE);
    uint8_t* lut = (uint8_t*)(ws + OFF_LUT);
    uint8_t* wqp = (uint8_t*)(ws + OFF_WQP);
    uint8_t* wqn = (uint8_t*)(ws + OFF_WQN);
    uint8_t* xq  = (uint8_t*)(ws + OFF_XQ);
    uint8_t* wby = (uint8_t*)(ws + OFF_WBY);

    const bool wby_ok = (ws_size >= (size_t)WS_NEED_WBY);   // deterministic

    k_prep_w<<<128, 256, 0, stream>>>(w, norm, wqp, wqn, wby, wby_ok ? 1 : 0);
    k_prep_x<<<576, 256, 0, stream>>>(x, xq, maxv);
    if (wby_ok)
        k_max_t<true><<<1024, 512, 0, stream>>>(xq, wqp, wqn, wby, maxv);
    else
        k_max_t<false><<<1024, 512, 0, stream>>>(xq, wqp, wqn, wby, maxv);
    k_lut<<<NROW, 256, 0, stream>>>(maxv, lut, mb, pmode);
    if (wby_ok)
        k_adc_t<true><<<1024, 512, 0, stream>>>(xq, wqp, wqn, wby, maxv, lut, mb, pmode, norm, out);
    else
        k_adc_t<false><<<1024, 512, 0, stream>>>(xq, wqp, wqn, wby, maxv, lut, mb, pmode, norm, out);
}

// Round 8
// 170.389 us; speedup vs baseline: 3.5458x; 3.5458x over previous
//
#include <hip/hip_runtime.h>
#include <stdint.h>

#define B_    2
#define CIN   128
#define HIMG  32
#define WIMG  32
#define COUT_ 128
#define PP    1024
#define FTOT  1152
#define NSUB  9
#define NS    8
#define NT    8
#define NROW  18

typedef int v4i __attribute__((ext_vector_type(4)));

// ws layout (bytes) — 2.66 MB (r4-proven footprint)
#define OFF_NORM   0                      // 128 f32
#define OFF_MAXV   512                    // 18 u32
#define OFF_MB     640                    // 18 uint2 (m, b)
#define OFF_PMODE  800                    // 18 i32
#define OFF_LUT    1024                   // 18*132 u8 (fallback gather table)
#define OFF_WQP    4096                   // 128*1152 u8 (packed magnitudes)
#define OFF_WQN    (4096 + 147456)
#define OFF_XQ     (4096 + 2*147456)      // 2*1024*1152 u8

// ---------------------------------------------------------------------------
// Weight prep (r4-proven): per-o norm, f64 quantization, |wi| u8 per sign.
// ---------------------------------------------------------------------------
__global__ __launch_bounds__(256) void k_prep_w(const float* __restrict__ w,
                                                float* __restrict__ norm_out,
                                                uint8_t* __restrict__ wqp,
                                                uint8_t* __restrict__ wqn) {
    int o = blockIdx.x, tid = threadIdx.x;
    __shared__ float red[256];
    const float* wo = w + (size_t)o * FTOT;
    float m = 0.f;
    for (int f = tid; f < FTOT; f += 256) m = fmaxf(m, fabsf(wo[f]));
    red[tid] = m;
    __syncthreads();
    for (int s2 = 128; s2 > 0; s2 >>= 1) {
        if (tid < s2) red[tid] = fmaxf(red[tid], red[tid + s2]);
        __syncthreads();
    }
    float norm = red[0];
    if (tid == 0) norm_out[o] = norm;
    for (int f = tid; f < FTOT; f += 256) {
        double wi = rint(((double)wo[f] / (double)norm) * 255.0);
        wqp[(size_t)o * FTOT + f] = (uint8_t)(int)fmax(wi, 0.0);
        wqn[(size_t)o * FTOT + f] = (uint8_t)(int)fmax(-wi, 0.0);
    }
}

// ---------------------------------------------------------------------------
// Input prep (r4-proven): im2col + quantize to u8 xq[b][p][f]; zero maxv.
// ---------------------------------------------------------------------------
__global__ __launch_bounds__(256) void k_prep_x(const float* __restrict__ x,
                                                uint8_t* __restrict__ xq,
                                                uint32_t* __restrict__ maxv) {
    if (blockIdx.x == 0 && threadIdx.x < NROW) maxv[threadIdx.x] = 0u;
    int gid = blockIdx.x * 256 + threadIdx.x;    // 2*1024*72 = 147456 exact
    int fg = gid % 72;
    int rest = gid / 72;
    int p = rest & 1023;
    int b = rest >> 10;
    int py = p >> 5, px = p & 31;
    uint32_t dw[4] = {0, 0, 0, 0};
    #pragma unroll
    for (int j = 0; j < 16; ++j) {
        int f = fg * 16 + j;
        int c = f / 9, u = f % 9;
        int kh = u / 3, kw = u % 3;
        int y = py + kh - 1, xx = px + kw - 1;
        uint32_t xi = 0;
        if (y >= 0 && y < HIMG && xx >= 0 && xx < WIMG) {
            float v = x[(((size_t)b * CIN + c) * HIMG + y) * WIMG + xx];
            float q = rintf(v * 256.0f);              // exact: power-of-2 scale
            q = fminf(fmaxf(q, 0.f), 255.f);
            xi = (uint32_t)q;
        }
        dw[j >> 2] |= xi << ((j & 3) * 8);
    }
    *reinterpret_cast<uint4*>(xq + (size_t)((b << 10) + p) * FTOT + fg * 16) =
        make_uint4(dw[0], dw[1], dw[2], dw[3]);
}

// Extract bit `sh` of each packed byte -> 0/1 bytes (i8 MFMA fragment).
__device__ __forceinline__ v4i bitsel(uint4 d, int sh) {
    v4i r;
    r[0] = (int)((d.x >> sh) & 0x01010101u);
    r[1] = (int)((d.y >> sh) & 0x01010101u);
    r[2] = (int)((d.z >> sh) & 0x01010101u);
    r[3] = (int)((d.w >> sh) & 0x01010101u);
    return r;
}

// ---------------------------------------------------------------------------
// Pass 1: max pr per (sub, sign). r4 block shape (512 thr = (b,ot,pt)) but
// wave = t: w-frags bitsel'd once per sub (0.5 op/pr), x bitsel'd per s.
// ---------------------------------------------------------------------------
__global__ __launch_bounds__(512) void k_max(const uint8_t* __restrict__ xq,
                                             const uint8_t* __restrict__ wqp,
                                             const uint8_t* __restrict__ wqn,
                                             uint32_t* __restrict__ maxv) {
    int tid = threadIdx.x, lane = tid & 63, wid = tid >> 6;
    int blk = blockIdx.x;
    int b = blk >> 9, r = blk & 511, ot = r >> 6, pt = r & 63;
    int t = wid;
    int col = lane & 15, kq = lane >> 4;
    int p = pt * 16 + col, oa = ot * 16 + col;
    __shared__ uint32_t smax[8][NSUB][2];

    const uint8_t* xbase = xq + (size_t)((b << 10) + p) * FTOT + kq * 16;
    const uint8_t* wpb = wqp + (size_t)oa * FTOT + kq * 16;
    const uint8_t* wnb = wqn + (size_t)oa * FTOT + kq * 16;

    for (int sub = 0; sub < NSUB; ++sub) {
        int fo = sub * 128;
        uint4 wp0 = *(const uint4*)(wpb + fo), wp1 = *(const uint4*)(wpb + fo + 64);
        uint4 wn0 = *(const uint4*)(wnb + fo), wn1 = *(const uint4*)(wnb + fo + 64);
        v4i ap0 = bitsel(wp0, t), ap1 = bitsel(wp1, t);
        v4i an0 = bitsel(wn0, t), an1 = bitsel(wn1, t);
        uint4 xg0 = *(const uint4*)(xbase + fo);
        uint4 xg1 = *(const uint4*)(xbase + fo + 64);

        int mp = 0, mn = 0;
        #pragma unroll
        for (int s = 0; s < NS; ++s) {
            v4i bf0 = bitsel(xg0, s), bf1 = bitsel(xg1, s);
            v4i acc = {0, 0, 0, 0};
            acc = __builtin_amdgcn_mfma_i32_16x16x64_i8(ap0, bf0, acc, 0, 0, 0);
            acc = __builtin_amdgcn_mfma_i32_16x16x64_i8(ap1, bf1, acc, 0, 0, 0);
            mp = max(mp, max(max(acc[0], acc[1]), max(acc[2], acc[3])));
            v4i acn = {0, 0, 0, 0};
            acn = __builtin_amdgcn_mfma_i32_16x16x64_i8(an0, bf0, acn, 0, 0, 0);
            acn = __builtin_amdgcn_mfma_i32_16x16x64_i8(an1, bf1, acn, 0, 0, 0);
            mn = max(mn, max(max(acn[0], acn[1]), max(acn[2], acn[3])));
        }
        #pragma unroll
        for (int off = 32; off > 0; off >>= 1) {
            mp = max(mp, __shfl_xor(mp, off));
            mn = max(mn, __shfl_xor(mn, off));
        }
        if (lane == 0) { smax[wid][sub][0] = (uint32_t)mp; smax[wid][sub][1] = (uint32_t)mn; }
    }
    __syncthreads();
    if (tid < NROW) {
        int sub = tid >> 1, sg = tid & 1;
        uint32_t m = 0;
        #pragma unroll
        for (int w2 = 0; w2 < 8; ++w2) m = max(m, smax[w2][sub][sg]);
        atomicMax(&maxv[tid], m);
    }
}

// ---------------------------------------------------------------------------
// k_lut (r6-proven): exact f64 table; integer (m,b) feasibility search with
// floor((pr*m+b)/2^16) == code(pr) for all pr<=vmax; fallback global LUT.
// ---------------------------------------------------------------------------
__global__ __launch_bounds__(256) void k_lut(const uint32_t* __restrict__ maxv,
                                             uint8_t* __restrict__ lut,
                                             uint2* __restrict__ mb,
                                             int* __restrict__ pmode) {
    int row = blockIdx.x, tid = threadIdx.x;
    __shared__ uint8_t codes[132];
    __shared__ int bestm;
    if (tid == 0) bestm = 0x7fffffff;
    int vmax = (int)maxv[row];
    for (int pr = tid; pr < 129; pr += 256) {
        double vmaxd = fmax((double)vmax, 1e-6);
        double step = vmaxd / 15.0;
        double q = rint((double)pr / step);
        q = fmin(fmax(q, 0.0), 15.0);
        codes[pr] = (uint8_t)q;
        lut[row * 132 + pr] = (uint8_t)q;
    }
    __syncthreads();
    int ve = max(vmax, 1);
    int m0 = (983040 + ve / 2) / ve;           // ~2^16*15/vmax
    int m = m0 - 128 + tid;
    if (m >= 1) {
        int L = 0, U = 0x7fffffff;
        for (int pr = 0; pr <= vmax && pr <= 128; ++pr) {
            int c = codes[pr];
            int lo = (c << 16) - pr * m;
            int hi = ((c + 1) << 16) - 1 - pr * m;
            L = max(L, lo);
            U = min(U, hi);
            if (L > U) break;
        }
        if (L <= U) atomicMin(&bestm, m);
    }
    __syncthreads();
    if (tid == 0) {
        if (bestm == 0x7fffffff) {
            pmode[row] = 1;
            mb[row] = make_uint2(0u, 0u);
        } else {
            int L = 0;
            for (int pr = 0; pr <= vmax && pr <= 128; ++pr)
                L = max(L, ((int)codes[pr] << 16) - pr * bestm);
            pmode[row] = 0;
            mb[row] = make_uint2((uint32_t)bestm, (uint32_t)L);
        }
    }
}

// ---------------------------------------------------------------------------
// Pass 2: wave = t; integer-mad ADC (3 VALU/pr, no LDS LUT); exact integer
// weighted sums; f64 final scale. Epilogue identical to r4 (proven mapping).
// ---------------------------------------------------------------------------
__global__ __launch_bounds__(512) void k_adc(const uint8_t* __restrict__ xq,
                                             const uint8_t* __restrict__ wqp,
                                             const uint8_t* __restrict__ wqn,
                                             const uint32_t* __restrict__ maxv,
                                             const uint8_t* __restrict__ lut,
                                             const uint2* __restrict__ mb,
                                             const int* __restrict__ pmode,
                                             const float* __restrict__ norm,
                                             float* __restrict__ out) {
    int tid = threadIdx.x, lane = tid & 63, wid = tid >> 6;
    int blk = blockIdx.x;
    int b = blk >> 9, r = blk & 511, ot = r >> 6, pt = r & 63;
    int t = wid;
    int col = lane & 15, kq = lane >> 4;
    int p = pt * 16 + col, oa = ot * 16 + col;

    __shared__ int lred[8][64][4];

    const uint8_t* xbase = xq + (size_t)((b << 10) + p) * FTOT + kq * 16;
    const uint8_t* wpb = wqp + (size_t)oa * FTOT + kq * 16;
    const uint8_t* wnb = wqn + (size_t)oa * FTOT + kq * 16;

    int run[4] = {0, 0, 0, 0};
    for (int sub = 0; sub < NSUB; ++sub) {
        int fo = sub * 128;
        uint4 wp0 = *(const uint4*)(wpb + fo), wp1 = *(const uint4*)(wpb + fo + 64);
        uint4 wn0 = *(const uint4*)(wnb + fo), wn1 = *(const uint4*)(wnb + fo + 64);
        v4i ap0 = bitsel(wp0, t), ap1 = bitsel(wp1, t);
        v4i an0 = bitsel(wn0, t), an1 = bitsel(wn1, t);
        uint4 xg0 = *(const uint4*)(xbase + fo);
        uint4 xg1 = *(const uint4*)(xbase + fo + 64);

        int rowp = sub * 2, rown = sub * 2 + 1;
        uint2 mbp = mb[rowp], mbn = mb[rown];
        int fbp = pmode[rowp], fbn = pmode[rown];
        const uint8_t* glp = lut + rowp * 132;
        const uint8_t* gln = lut + rown * 132;
        int vp = (int)maxv[rowp], vn = (int)maxv[rown];

        uint32_t Sp[4] = {0, 0, 0, 0}, Sn[4] = {0, 0, 0, 0};
        #pragma unroll
        for (int s = 0; s < NS; ++s) {
            v4i bf0 = bitsel(xg0, s), bf1 = bitsel(xg1, s);
            v4i acc = {0, 0, 0, 0};
            acc = __builtin_amdgcn_mfma_i32_16x16x64_i8(ap0, bf0, acc, 0, 0, 0);
            acc = __builtin_amdgcn_mfma_i32_16x16x64_i8(ap1, bf1, acc, 0, 0, 0);
            if (fbp == 0) {
                #pragma unroll
                for (int i = 0; i < 4; ++i) {
                    uint32_t v = __umul24((uint32_t)acc[i], mbp.x) + mbp.y;
                    Sp[i] += ((v >> 16) & 15u) << s;
                }
            } else {
                #pragma unroll
                for (int i = 0; i < 4; ++i) Sp[i] += (uint32_t)glp[acc[i]] << s;
            }
            v4i acn = {0, 0, 0, 0};
            acn = __builtin_amdgcn_mfma_i32_16x16x64_i8(an0, bf0, acn, 0, 0, 0);
            acn = __builtin_amdgcn_mfma_i32_16x16x64_i8(an1, bf1, acn, 0, 0, 0);
            if (fbn == 0) {
                #pragma unroll
                for (int i = 0; i < 4; ++i) {
                    uint32_t v = __umul24((uint32_t)acn[i], mbn.x) + mbn.y;
                    Sn[i] += ((v >> 16) & 15u) << s;
                }
            } else {
                #pragma unroll
                for (int i = 0; i < 4; ++i) Sn[i] += (uint32_t)gln[acn[i]] << s;
            }
        }
        // exact: Sp,Sn <= 15*255 = 3825 < 2^12; vp*Sp < 2^19; <<t(<=7) < 2^26;
        // 9-sub sum < 2^30 — int32 safe. 2^s folded in Sp, 2^t applied here.
        #pragma unroll
        for (int i = 0; i < 4; ++i) {
            int d = (int)__umul24((uint32_t)vp, Sp[i]) - (int)__umul24((uint32_t)vn, Sn[i]);
            run[i] += (int)((uint32_t)d << t);
        }
    }
    #pragma unroll
    for (int i = 0; i < 4; ++i) lred[wid][lane][i] = run[i];
    __syncthreads();
    if (tid < 256) {
        int lane2 = tid >> 2, i = tid & 3;
        long long s64 = 0;
        #pragma unroll
        for (int w2 = 0; w2 < 8; ++w2) s64 += (long long)lred[w2][lane2][i];
        int o = ot * 16 + (lane2 >> 4) * 4 + i;      // C/D: row=(lane>>4)*4+reg [m89]
        int pp2 = pt * 16 + (lane2 & 15);            // C/D: col=lane&15
        double v = (double)s64 * (double)norm[o] / 15.0 / 255.0 / 256.0;
        out[((size_t)(b * COUT_ + o)) * PP + pp2] = (float)v;
    }
    if (blk == 0 && tid == 0) out[(size_t)B_ * COUT_ * PP] = 0.0f;   // adc_loss
}

// ---------------------------------------------------------------------------
extern "C" void kernel_launch(void* const* d_in, const int* in_sizes, int n_in,
                              void* d_out, int out_size, void* d_ws, size_t ws_size,
                              hipStream_t stream) {
    const float* x = (const float*)d_in[0];
    const float* w = (const float*)d_in[1];
    float* out = (float*)d_out;
    char* ws = (char*)d_ws;

    float* norm = (float*)(ws + OFF_NORM);
    uint32_t* maxv = (uint32_t*)(ws + OFF_MAXV);
    uint2* mb = (uint2*)(ws + OFF_MB);
    int* pmode = (int*)(ws + OFF_PMODE);
    uint8_t* lut = (uint8_t*)(ws + OFF_LUT);
    uint8_t* wqp = (uint8_t*)(ws + OFF_WQP);
    uint8_t* wqn = (uint8_t*)(ws + OFF_WQN);
    uint8_t* xq  = (uint8_t*)(ws + OFF_XQ);

    k_prep_w<<<128, 256, 0, stream>>>(w, norm, wqp, wqn);
    k_prep_x<<<576, 256, 0, stream>>>(x, xq, maxv);
    k_max<<<1024, 512, 0, stream>>>(xq, wqp, wqn, maxv);
    k_lut<<<NROW, 256, 0, stream>>>(maxv, lut, mb, pmode);
    k_adc<<<1024, 512, 0, stream>>>(xq, wqp, wqn, maxv, lut, mb, pmode, norm, out);
}

// Round 9
// 150.474 us; speedup vs baseline: 4.0151x; 1.1323x over previous
//
#include <hip/hip_runtime.h>
#include <stdint.h>

#define B_    2
#define CIN   128
#define HIMG  32
#define WIMG  32
#define COUT_ 128
#define PP    1024
#define FTOT  1152
#define NSUB  9
#define NS    8
#define NT    8
#define NROW  18

typedef int v4i __attribute__((ext_vector_type(4)));

// ws layout (bytes) — 2.66 MB (proven footprint)
#define OFF_NORM   0                      // 128 f32
#define OFF_MAXV   512                    // 18 u32
#define OFF_MB     640                    // 18 uint2 (m, b)
#define OFF_PMODE  800                    // 18 i32
#define OFF_LUT    1024                   // 18*132 u8 (fallback gather table)
#define OFF_WQP    4096                   // 128*1152 u8 (packed magnitudes)
#define OFF_WQN    (4096 + 147456)
#define OFF_XQ     (4096 + 2*147456)      // 2*1024*1152 u8

// XOR swizzle within a 128B o-row: spreads the 16-lane same-column reads
// across 8 bank groups (2-way residual = free, m136). a1 = a0 ^ 64 stays
// in-row because bit6 of (kq*16) is 0.
#define SWZ16(o, koff) ((koff) ^ (((o) & 7) << 4))

// ---------------------------------------------------------------------------
// Weight prep (proven): per-o norm, f64 quantization, |wi| u8 per sign.
// ---------------------------------------------------------------------------
__global__ __launch_bounds__(256) void k_prep_w(const float* __restrict__ w,
                                                float* __restrict__ norm_out,
                                                uint8_t* __restrict__ wqp,
                                                uint8_t* __restrict__ wqn) {
    int o = blockIdx.x, tid = threadIdx.x;
    __shared__ float red[256];
    const float* wo = w + (size_t)o * FTOT;
    float m = 0.f;
    for (int f = tid; f < FTOT; f += 256) m = fmaxf(m, fabsf(wo[f]));
    red[tid] = m;
    __syncthreads();
    for (int s2 = 128; s2 > 0; s2 >>= 1) {
        if (tid < s2) red[tid] = fmaxf(red[tid], red[tid + s2]);
        __syncthreads();
    }
    float norm = red[0];
    if (tid == 0) norm_out[o] = norm;
    for (int f = tid; f < FTOT; f += 256) {
        double wi = rint(((double)wo[f] / (double)norm) * 255.0);
        wqp[(size_t)o * FTOT + f] = (uint8_t)(int)fmax(wi, 0.0);
        wqn[(size_t)o * FTOT + f] = (uint8_t)(int)fmax(-wi, 0.0);
    }
}

// ---------------------------------------------------------------------------
// Input prep (proven): im2col + quantize to u8 xq[b][p][f]; zero maxv.
// ---------------------------------------------------------------------------
__global__ __launch_bounds__(256) void k_prep_x(const float* __restrict__ x,
                                                uint8_t* __restrict__ xq,
                                                uint32_t* __restrict__ maxv) {
    if (blockIdx.x == 0 && threadIdx.x < NROW) maxv[threadIdx.x] = 0u;
    int gid = blockIdx.x * 256 + threadIdx.x;    // 2*1024*72 = 147456 exact
    int fg = gid % 72;
    int rest = gid / 72;
    int p = rest & 1023;
    int b = rest >> 10;
    int py = p >> 5, px = p & 31;
    uint32_t dw[4] = {0, 0, 0, 0};
    #pragma unroll
    for (int j = 0; j < 16; ++j) {
        int f = fg * 16 + j;
        int c = f / 9, u = f % 9;
        int kh = u / 3, kw = u % 3;
        int y = py + kh - 1, xx = px + kw - 1;
        uint32_t xi = 0;
        if (y >= 0 && y < HIMG && xx >= 0 && xx < WIMG) {
            float v = x[(((size_t)b * CIN + c) * HIMG + y) * WIMG + xx];
            float q = rintf(v * 256.0f);              // exact: power-of-2 scale
            q = fminf(fmaxf(q, 0.f), 255.f);
            xi = (uint32_t)q;
        }
        dw[j >> 2] |= xi << ((j & 3) * 8);
    }
    *reinterpret_cast<uint4*>(xq + (size_t)((b << 10) + p) * FTOT + fg * 16) =
        make_uint4(dw[0], dw[1], dw[2], dw[3]);
}

// Extract bit `sh` of each packed byte -> 0/1 bytes (i8 MFMA fragment).
__device__ __forceinline__ v4i bitsel(uint4 d, int sh) {
    v4i r;
    r[0] = (int)((d.x >> sh) & 0x01010101u);
    r[1] = (int)((d.y >> sh) & 0x01010101u);
    r[2] = (int)((d.z >> sh) & 0x01010101u);
    r[3] = (int)((d.w >> sh) & 0x01010101u);
    return r;
}

// ---------------------------------------------------------------------------
// Pass 1: max pr per (sub, sign). Block(512)=(b,ot,pt), wave = s.
// W bit-planes staged per (block,sub) into LDS; A-frags via ds_read_b128.
// ---------------------------------------------------------------------------
__global__ __launch_bounds__(512) void k_max(const uint8_t* __restrict__ xq,
                                             const uint8_t* __restrict__ wqp,
                                             const uint8_t* __restrict__ wqn,
                                             uint32_t* __restrict__ maxv) {
    int tid = threadIdx.x, lane = tid & 63, wid = tid >> 6;
    int blk = blockIdx.x;
    int b = blk >> 9, r = blk & 511, ot = r >> 6, pt = r & 63;
    int s = wid;
    int col = lane & 15, kq = lane >> 4;
    int p = pt * 16 + col;

    __shared__ uint8_t wlds[32768];               // 16 planes x [16 o][128 k]
    __shared__ uint32_t smax[8][NSUB][2];

    const uint8_t* xbase = xq + (size_t)((b << 10) + p) * FTOT + kq * 16;
    int a0 = col * 128 + SWZ16(col, kq * 16);
    int a1 = a0 ^ 64;

    // staging role: item = (sign, o, kq8); each thread covers 4 t-planes
    int it = tid >> 1, th = tid & 1;
    int skq = it & 7, so = (it >> 3) & 15, ssign = it >> 7;
    const uint8_t* ssrc = (ssign ? wqn : wqp) + (size_t)(ot * 16 + so) * FTOT + skq * 16;
    int swb = so * 128 + SWZ16(so, skq * 16);

    for (int sub = 0; sub < NSUB; ++sub) {
        {
            uint4 d = *(const uint4*)(ssrc + sub * 128);
            #pragma unroll
            for (int j = 0; j < 4; ++j) {
                int t = th * 4 + j;
                *(v4i*)&wlds[(t * 2 + ssign) * 2048 + swb] = bitsel(d, t);
            }
        }
        __syncthreads();

        uint4 xg0 = *(const uint4*)(xbase + sub * 128);
        uint4 xg1 = *(const uint4*)(xbase + sub * 128 + 64);
        v4i bf0 = bitsel(xg0, s), bf1 = bitsel(xg1, s);

        int mp = 0, mn = 0;
        #pragma unroll
        for (int t = 0; t < NT; ++t) {
            v4i ap0 = *(const v4i*)&wlds[(t * 2 + 0) * 2048 + a0];
            v4i ap1 = *(const v4i*)&wlds[(t * 2 + 0) * 2048 + a1];
            v4i an0 = *(const v4i*)&wlds[(t * 2 + 1) * 2048 + a0];
            v4i an1 = *(const v4i*)&wlds[(t * 2 + 1) * 2048 + a1];
            v4i acc = {0, 0, 0, 0};
            acc = __builtin_amdgcn_mfma_i32_16x16x64_i8(ap0, bf0, acc, 0, 0, 0);
            acc = __builtin_amdgcn_mfma_i32_16x16x64_i8(ap1, bf1, acc, 0, 0, 0);
            mp = max(mp, max(max(acc[0], acc[1]), max(acc[2], acc[3])));
            v4i acn = {0, 0, 0, 0};
            acn = __builtin_amdgcn_mfma_i32_16x16x64_i8(an0, bf0, acn, 0, 0, 0);
            acn = __builtin_amdgcn_mfma_i32_16x16x64_i8(an1, bf1, acn, 0, 0, 0);
            mn = max(mn, max(max(acn[0], acn[1]), max(acn[2], acn[3])));
        }
        #pragma unroll
        for (int off = 32; off > 0; off >>= 1) {
            mp = max(mp, __shfl_xor(mp, off));
            mn = max(mn, __shfl_xor(mn, off));
        }
        if (lane == 0) { smax[wid][sub][0] = (uint32_t)mp; smax[wid][sub][1] = (uint32_t)mn; }
        __syncthreads();                       // drain reads before restage
    }
    if (tid < NROW) {
        int sub = tid >> 1, sg = tid & 1;
        uint32_t m = 0;
        #pragma unroll
        for (int w2 = 0; w2 < 8; ++w2) m = max(m, smax[w2][sub][sg]);
        atomicMax(&maxv[tid], m);
    }
}

// ---------------------------------------------------------------------------
// k_lut (proven): exact f64 table; integer (m,b) feasibility search with
// floor((pr*m+b)/2^16) == code(pr) for all pr<=vmax; fallback global LUT.
// ---------------------------------------------------------------------------
__global__ __launch_bounds__(256) void k_lut(const uint32_t* __restrict__ maxv,
                                             uint8_t* __restrict__ lut,
                                             uint2* __restrict__ mb,
                                             int* __restrict__ pmode) {
    int row = blockIdx.x, tid = threadIdx.x;
    __shared__ uint8_t codes[132];
    __shared__ int bestm;
    if (tid == 0) bestm = 0x7fffffff;
    int vmax = (int)maxv[row];
    for (int pr = tid; pr < 129; pr += 256) {
        double vmaxd = fmax((double)vmax, 1e-6);
        double step = vmaxd / 15.0;
        double q = rint((double)pr / step);
        q = fmin(fmax(q, 0.0), 15.0);
        codes[pr] = (uint8_t)q;
        lut[row * 132 + pr] = (uint8_t)q;
    }
    __syncthreads();
    int ve = max(vmax, 1);
    int m0 = (983040 + ve / 2) / ve;           // ~2^16*15/vmax
    int m = m0 - 128 + tid;
    if (m >= 1) {
        int L = 0, U = 0x7fffffff;
        for (int pr = 0; pr <= vmax && pr <= 128; ++pr) {
            int c = codes[pr];
            int lo = (c << 16) - pr * m;
            int hi = ((c + 1) << 16) - 1 - pr * m;
            L = max(L, lo);
            U = min(U, hi);
            if (L > U) break;
        }
        if (L <= U) atomicMin(&bestm, m);
    }
    __syncthreads();
    if (tid == 0) {
        if (bestm == 0x7fffffff) {
            pmode[row] = 1;
            mb[row] = make_uint2(0u, 0u);
        } else {
            int L = 0;
            for (int pr = 0; pr <= vmax && pr <= 128; ++pr)
                L = max(L, ((int)codes[pr] << 16) - pr * bestm);
            pmode[row] = 0;
            mb[row] = make_uint2((uint32_t)bestm, (uint32_t)L);
        }
    }
}

// ---------------------------------------------------------------------------
// Pass 2: same staged structure; int-mad ADC (3 VALU/pr, exact); integer
// weighted sums (2^(s+t) folded, r4-proven bounds); f64 final scale.
// lred aliases wlds (dead after last compute barrier).
// ---------------------------------------------------------------------------
__global__ __launch_bounds__(512) void k_adc(const uint8_t* __restrict__ xq,
                                             const uint8_t* __restrict__ wqp,
                                             const uint8_t* __restrict__ wqn,
                                             const uint32_t* __restrict__ maxv,
                                             const uint8_t* __restrict__ lut,
                                             const uint2* __restrict__ mb,
                                             const int* __restrict__ pmode,
                                             const float* __restrict__ norm,
                                             float* __restrict__ out) {
    int tid = threadIdx.x, lane = tid & 63, wid = tid >> 6;
    int blk = blockIdx.x;
    int b = blk >> 9, r = blk & 511, ot = r >> 6, pt = r & 63;
    int s = wid;
    int col = lane & 15, kq = lane >> 4;
    int p = pt * 16 + col;

    __shared__ uint8_t wlds[32768];
    int (*lred)[64][4] = (int (*)[64][4])wlds;     // alias, used after loop

    const uint8_t* xbase = xq + (size_t)((b << 10) + p) * FTOT + kq * 16;
    int a0 = col * 128 + SWZ16(col, kq * 16);
    int a1 = a0 ^ 64;

    int it = tid >> 1, th = tid & 1;
    int skq = it & 7, so = (it >> 3) & 15, ssign = it >> 7;
    const uint8_t* ssrc = (ssign ? wqn : wqp) + (size_t)(ot * 16 + so) * FTOT + skq * 16;
    int swb = so * 128 + SWZ16(so, skq * 16);

    int run[4] = {0, 0, 0, 0};
    for (int sub = 0; sub < NSUB; ++sub) {
        {
            uint4 d = *(const uint4*)(ssrc + sub * 128);
            #pragma unroll
            for (int j = 0; j < 4; ++j) {
                int t = th * 4 + j;
                *(v4i*)&wlds[(t * 2 + ssign) * 2048 + swb] = bitsel(d, t);
            }
        }
        __syncthreads();

        uint4 xg0 = *(const uint4*)(xbase + sub * 128);
        uint4 xg1 = *(const uint4*)(xbase + sub * 128 + 64);
        v4i bf0 = bitsel(xg0, s), bf1 = bitsel(xg1, s);

        int rowp = sub * 2, rown = sub * 2 + 1;
        uint2 mbp = mb[rowp], mbn = mb[rown];
        int fbp = pmode[rowp], fbn = pmode[rown];
        const uint8_t* glp = lut + rowp * 132;
        const uint8_t* gln = lut + rown * 132;
        int vp = (int)maxv[rowp], vn = (int)maxv[rown];

        uint32_t Sp[4] = {0, 0, 0, 0}, Sn[4] = {0, 0, 0, 0};
        #pragma unroll
        for (int t = 0; t < NT; ++t) {
            v4i ap0 = *(const v4i*)&wlds[(t * 2 + 0) * 2048 + a0];
            v4i ap1 = *(const v4i*)&wlds[(t * 2 + 0) * 2048 + a1];
            v4i an0 = *(const v4i*)&wlds[(t * 2 + 1) * 2048 + a0];
            v4i an1 = *(const v4i*)&wlds[(t * 2 + 1) * 2048 + a1];
            v4i acc = {0, 0, 0, 0};
            acc = __builtin_amdgcn_mfma_i32_16x16x64_i8(ap0, bf0, acc, 0, 0, 0);
            acc = __builtin_amdgcn_mfma_i32_16x16x64_i8(ap1, bf1, acc, 0, 0, 0);
            if (fbp == 0) {
                #pragma unroll
                for (int i = 0; i < 4; ++i) {
                    uint32_t q = ((__umul24((uint32_t)acc[i], mbp.x) + mbp.y) >> 16) & 15u;
                    Sp[i] += q << (s + t);
                }
            } else {
                #pragma unroll
                for (int i = 0; i < 4; ++i) Sp[i] += (uint32_t)glp[acc[i]] << (s + t);
            }
            v4i acn = {0, 0, 0, 0};
            acn = __builtin_amdgcn_mfma_i32_16x16x64_i8(an0, bf0, acn, 0, 0, 0);
            acn = __builtin_amdgcn_mfma_i32_16x16x64_i8(an1, bf1, acn, 0, 0, 0);
            if (fbn == 0) {
                #pragma unroll
                for (int i = 0; i < 4; ++i) {
                    uint32_t q = ((__umul24((uint32_t)acn[i], mbn.x) + mbn.y) >> 16) & 15u;
                    Sn[i] += q << (s + t);
                }
            } else {
                #pragma unroll
                for (int i = 0; i < 4; ++i) Sn[i] += (uint32_t)gln[acn[i]] << (s + t);
            }
        }
        // exact: Sp <= 15*255*2^s < 2^19; vp*Sp < 2^26; 9-sub sum < 2^31
        #pragma unroll
        for (int i = 0; i < 4; ++i)
            run[i] += (int)__umul24((uint32_t)vp, Sp[i]) - (int)__umul24((uint32_t)vn, Sn[i]);
        __syncthreads();                       // drain reads before restage/alias
    }

    #pragma unroll
    for (int i = 0; i < 4; ++i) lred[wid][lane][i] = run[i];
    __syncthreads();
    if (tid < 256) {
        int lane2 = tid >> 2, i = tid & 3;
        long long s64 = 0;
        #pragma unroll
        for (int w2 = 0; w2 < 8; ++w2) s64 += (long long)lred[w2][lane2][i];
        int o = ot * 16 + (lane2 >> 4) * 4 + i;      // C/D: row=(lane>>4)*4+reg [m89]
        int pp2 = pt * 16 + (lane2 & 15);            // C/D: col=lane&15
        double v = (double)s64 * (double)norm[o] / 15.0 / 255.0 / 256.0;
        out[((size_t)(b * COUT_ + o)) * PP + pp2] = (float)v;
    }
    if (blk == 0 && tid == 0) out[(size_t)B_ * COUT_ * PP] = 0.0f;   // adc_loss
}

// ---------------------------------------------------------------------------
extern "C" void kernel_launch(void* const* d_in, const int* in_sizes, int n_in,
                              void* d_out, int out_size, void* d_ws, size_t ws_size,
                              hipStream_t stream) {
    const float* x = (const float*)d_in[0];
    const float* w = (const float*)d_in[1];
    float* out = (float*)d_out;
    char* ws = (char*)d_ws;

    float* norm = (float*)(ws + OFF_NORM);
    uint32_t* maxv = (uint32_t*)(ws + OFF_MAXV);
    uint2* mb = (uint2*)(ws + OFF_MB);
    int* pmode = (int*)(ws + OFF_PMODE);
    uint8_t* lut = (uint8_t*)(ws + OFF_LUT);
    uint8_t* wqp = (uint8_t*)(ws + OFF_WQP);
    uint8_t* wqn = (uint8_t*)(ws + OFF_WQN);
    uint8_t* xq  = (uint8_t*)(ws + OFF_XQ);

    k_prep_w<<<128, 256, 0, stream>>>(w, norm, wqp, wqn);
    k_prep_x<<<576, 256, 0, stream>>>(x, xq, maxv);
    k_max<<<1024, 512, 0, stream>>>(xq, wqp, wqn, maxv);
    k_lut<<<NROW, 256, 0, stream>>>(maxv, lut, mb, pmode);
    k_adc<<<1024, 512, 0, stream>>>(xq, wqp, wqn, maxv, lut, mb, pmode, norm, out);
}